// Round 2
// baseline (7710.172 us; speedup 1.0000x reference)
//
#include <hip/hip_runtime.h>
#include <hip/hip_bf16.h>

#define NNODES 50000
#define TSTEPS 8
#define NEDGES 800000
#define VVOCAB 1000
#define DDIM 32
#define HDIM 128
#define G0DIM 64
#define H3 384

// ---------------- zero fill (replaces hipMemsetAsync for capture safety) ----------------
__global__ __launch_bounds__(256) void fill_zero(float* __restrict__ p, long long n) {
  long long i = (long long)blockIdx.x * 256 + threadIdx.x;
  long long stride = (long long)gridDim.x * 256;
  for (; i < n; i += stride) p[i] = 0.f;
}

// ---- static encoder + attention init: acc=se, mx=logit(se), s=1 ------------------------
__global__ __launch_bounds__(128) void static_encode_attn_init(
    const float* __restrict__ dense, const int* __restrict__ sparse,
    const float* __restrict__ emb,   // (2,V,16)
    const float* __restrict__ Ws, const float* __restrict__ bs,
    const float* __restrict__ Waw, const float* __restrict__ baw,
    float* __restrict__ acc, float* __restrict__ s, float* __restrict__ mx) {
  int n = blockIdx.x;
  int j = threadIdx.x; // 0..127
  __shared__ float xs[G0DIM];
  if (j < G0DIM) {
    float v;
    if (j < 16) {
      v = emb[sparse[n * 2 + 0] * 16 + j];
    } else if (j < 32) {
      v = emb[VVOCAB * 16 + sparse[n * 2 + 1] * 16 + (j - 16)];
    } else {
      v = dense[n * DDIM + (j - 32)];
    }
    xs[j] = v;
  }
  __syncthreads();
  float a = bs[j];
#pragma unroll 16
  for (int k = 0; k < G0DIM; ++k) a += xs[k] * Ws[k * HDIM + j];
  a = fmaxf(a, 0.f);
  // attention logit for tau=0
  float v = tanhf(a) * Waw[j];
  __shared__ float red[2];
  int lane = j & 63, wid = j >> 6;
#pragma unroll
  for (int off = 32; off > 0; off >>= 1) v += __shfl_down(v, off, 64);
  if (lane == 0) red[wid] = v;
  __syncthreads();
  acc[(size_t)n * HDIM + j] = a;  // weight exp(l-m)=1 since m=l
  if (j == 0) {
    s[n] = 1.f;
    mx[n] = red[0] + red[1] + baw[0];
  }
}

// ---------------- dynamic feature gather for one t: x = concat(embA,embB,dense) [N,64] ---
__global__ __launch_bounds__(256) void dynx_gather(
    const float* __restrict__ dense_t, const int* __restrict__ sparse_t,
    const float* __restrict__ emb, float* __restrict__ xout) {
  int idx = blockIdx.x * 256 + threadIdx.x;
  int n = idx >> 6, k = idx & 63;
  if (n >= NNODES) return;
  float v;
  if (k < 16)
    v = emb[sparse_t[n * 2 + 0] * 16 + k];
  else if (k < 32)
    v = emb[VVOCAB * 16 + sparse_t[n * 2 + 1] * 16 + (k - 16)];
  else
    v = dense_t[n * DDIM + (k - 32)];
  xout[idx] = v;
}

// ---------------- segment_sum via atomics: m[dst] += w * x[src], width D ----------------
template <int D>
__global__ __launch_bounds__(256) void scatter_add(
    const int* __restrict__ e_src, const int* __restrict__ e_dst,
    const float* __restrict__ w, const float* __restrict__ x,
    float* __restrict__ m) {
  long long idx = (long long)blockIdx.x * 256 + threadIdx.x;
  int e = (int)(idx / D);
  int k = (int)(idx & (D - 1));
  if (e >= NEDGES) return;
  int sidx = e_src[e];
  int d = e_dst[e];
  atomicAdd(&m[(size_t)d * D + k], w[e] * x[(size_t)sidx * D + k]);
}

// ---------------- small row matmul: y[n,:] = (relu?)(x[n,:] @ W + b), W is (K,128) ------
template <int K, int NB, bool RELU>
__global__ __launch_bounds__(128) void rowmm(
    const float* __restrict__ x, const float* __restrict__ W,
    const float* __restrict__ b, float* __restrict__ y, int nrows) {
  int n0 = blockIdx.x * NB;
  int j = threadIdx.x; // 0..127
  __shared__ float xs[NB][K];
  for (int i = j; i < NB * K; i += 128) {
    int nn = i / K, kk = i % K;
    xs[nn][kk] = (n0 + nn < nrows) ? x[(size_t)(n0 + nn) * K + kk] : 0.f;
  }
  __syncthreads();
  float bj = b[j];
  float acc[NB];
#pragma unroll
  for (int q = 0; q < NB; ++q) acc[q] = bj;
  for (int k = 0; k < K; ++k) {
    float wv = W[k * HDIM + j];
#pragma unroll
    for (int q = 0; q < NB; ++q) acc[q] += xs[q][k] * wv;
  }
#pragma unroll
  for (int q = 0; q < NB; ++q) {
    if (n0 + q < nrows)
      y[(size_t)(n0 + q) * HDIM + j] = RELU ? fmaxf(acc[q], 0.f) : acc[q];
  }
}

// ---------------- GRU step for NB nodes: 384 threads = 3 gates x 128 cols ---------------
template <int NB>
__global__ __launch_bounds__(384) void gru_step(
    const float* __restrict__ g, const float* __restrict__ hprev,
    const float* __restrict__ Wx, const float* __restrict__ Wh,
    const float* __restrict__ bx, const float* __restrict__ bh,
    float* __restrict__ hout, int nrows) {
  int n0 = blockIdx.x * NB;
  int j = threadIdx.x; // 0..383
  __shared__ float xv[NB][HDIM], hv[NB][HDIM];
  __shared__ float sum_rz[NB][256];
  __shared__ float xn_s[NB][HDIM], hn_s[NB][HDIM];
  for (int i = j; i < NB * HDIM; i += 384) {
    int nn = i >> 7, kk = i & 127;
    float xval = 0.f, hval = 0.f;
    if (n0 + nn < nrows) {
      xval = g[(size_t)(n0 + nn) * HDIM + kk];
      if (hprev) hval = hprev[(size_t)(n0 + nn) * HDIM + kk];
    }
    xv[nn][kk] = xval;
    hv[nn][kk] = hval;
  }
  __syncthreads();
  float accx[NB], acch[NB];
#pragma unroll
  for (int q = 0; q < NB; ++q) { accx[q] = 0.f; acch[q] = 0.f; }
  for (int k = 0; k < HDIM; ++k) {
    float wx = Wx[k * H3 + j];
    float wh = Wh[k * H3 + j];
#pragma unroll
    for (int q = 0; q < NB; ++q) {
      accx[q] += xv[q][k] * wx;
      acch[q] += hv[q][k] * wh;
    }
  }
  float bxj = bx[j], bhj = bh[j];
  if (j < 256) {
#pragma unroll
    for (int q = 0; q < NB; ++q) sum_rz[q][j] = (accx[q] + bxj) + (acch[q] + bhj);
  } else {
#pragma unroll
    for (int q = 0; q < NB; ++q) {
      xn_s[q][j - 256] = accx[q] + bxj;
      hn_s[q][j - 256] = acch[q] + bhj;
    }
  }
  __syncthreads();
  if (j < 128) {
#pragma unroll
    for (int q = 0; q < NB; ++q) {
      if (n0 + q < nrows) {
        float r = 1.f / (1.f + expf(-sum_rz[q][j]));
        float z = 1.f / (1.f + expf(-sum_rz[q][128 + j]));
        float nc = tanhf(xn_s[q][j] + r * hn_s[q][j]);
        hout[(size_t)(n0 + q) * HDIM + j] = (1.f - z) * nc + z * hv[q][j];
      }
    }
  }
}

// ---- online-softmax attention update with h_t ------------------------------------------
__global__ __launch_bounds__(128) void attn_update(
    const float* __restrict__ h, const float* __restrict__ Waw,
    const float* __restrict__ baw,
    float* __restrict__ acc, float* __restrict__ s, float* __restrict__ mx) {
  int n = blockIdx.x;
  int j = threadIdx.x;
  float hv = h[(size_t)n * HDIM + j];
  float v = tanhf(hv) * Waw[j];
  __shared__ float red[2];
  int lane = j & 63, wid = j >> 6;
#pragma unroll
  for (int off = 32; off > 0; off >>= 1) v += __shfl_down(v, off, 64);
  if (lane == 0) red[wid] = v;
  __syncthreads();
  float l = red[0] + red[1] + baw[0];
  float m = mx[n];
  float mnew = fmaxf(m, l);
  float factor = expf(m - mnew);
  float p = expf(l - mnew);
  acc[(size_t)n * HDIM + j] = acc[(size_t)n * HDIM + j] * factor + p * hv;
  if (j == 0) {
    s[n] = s[n] * factor + p;
    mx[n] = mnew;
  }
}

// ---- finalize: out /= s ------------------------------------------------------------------
__global__ __launch_bounds__(256) void attn_finalize(
    float* __restrict__ acc, const float* __restrict__ s) {
  int idx = blockIdx.x * 256 + threadIdx.x;
  if (idx >= NNODES * HDIM) return;
  acc[idx] = acc[idx] / s[idx >> 7];
}

extern "C" void kernel_launch(void* const* d_in, const int* in_sizes, int n_in,
                              void* d_out, int out_size, void* d_ws, size_t ws_size,
                              hipStream_t stream) {
  const float* static_dense = (const float*)d_in[0];
  const int*   static_sparse = (const int*)d_in[1];
  const float* dyn_dense = (const float*)d_in[2];
  const int*   dyn_sparse = (const int*)d_in[3];
  const int*   edges = (const int*)d_in[4];
  const float* weights = (const float*)d_in[5];
  const float* s_emb = (const float*)d_in[6];
  const float* d_emb = (const float*)d_in[7];
  const float* Ws = (const float*)d_in[8];
  const float* bs = (const float*)d_in[9];
  const float* gW1 = (const float*)d_in[10];
  const float* gb1 = (const float*)d_in[11];
  const float* gW2 = (const float*)d_in[12];
  const float* gb2 = (const float*)d_in[13];
  const float* Wx = (const float*)d_in[14];
  const float* Wh = (const float*)d_in[15];
  const float* bx = (const float*)d_in[16];
  const float* bh = (const float*)d_in[17];
  const float* Waw = (const float*)d_in[18];
  const float* baw = (const float*)d_in[19];
  float* out = (float*)d_out;  // doubles as attention accumulator [N,128]

  const size_t N = NNODES;
  float* ws = (float*)d_ws;
  // workspace layout (floats): total N*(2 + 128 + 128 + 128 + 128) = N*514 ~ 103MB
  float* sden = ws;                    // N      (softmax denom)
  float* mxv  = sden + N;              // N      (softmax running max)
  float* hA   = mxv + N;               // N*128
  float* hB   = hA + N * HDIM;         // N*128
  float* R1   = hB + N * HDIM;         // N*128: dynx(N*64) + m1(N*64), then m2(N*128)
  float* R2   = R1 + N * HDIM;         // N*128: h1, then gbuf
  float* dynx = R1;
  float* m1   = R1 + N * G0DIM;
  float* m2   = R1;
  float* h1   = R2;
  float* gbuf = R2;

  static_encode_attn_init<<<NNODES, 128, 0, stream>>>(
      static_dense, static_sparse, s_emb, Ws, bs, Waw, baw, out, sden, mxv);

  for (int t = 0; t < TSTEPS; ++t) {
    const int* e_src = edges + (size_t)t * 2 * NEDGES;
    const int* e_dst = e_src + NEDGES;
    const float* w_t = weights + (size_t)t * NEDGES;
    float* hcur = (t & 1) ? hB : hA;
    const float* hprev = (t == 0) ? nullptr : ((t & 1) ? hA : hB);

    dynx_gather<<<(NNODES * 64 + 255) / 256, 256, 0, stream>>>(
        dyn_dense + (size_t)t * N * DDIM, dyn_sparse + (size_t)t * N * 2, d_emb, dynx);

    fill_zero<<<2048, 256, 0, stream>>>(m1, (long long)N * G0DIM);
    {
      long long total = (long long)NEDGES * 64;
      scatter_add<64><<<(int)((total + 255) / 256), 256, 0, stream>>>(e_src, e_dst, w_t, dynx, m1);
    }
    rowmm<64, 8, true><<<(NNODES + 7) / 8, 128, 0, stream>>>(
        m1, gW1 + (size_t)t * G0DIM * HDIM, gb1 + (size_t)t * HDIM, h1, NNODES);

    fill_zero<<<2048, 256, 0, stream>>>(m2, (long long)N * HDIM);
    {
      long long total = (long long)NEDGES * 128;
      scatter_add<128><<<(int)((total + 255) / 256), 256, 0, stream>>>(e_src, e_dst, w_t, h1, m2);
    }
    rowmm<128, 8, false><<<(NNODES + 7) / 8, 128, 0, stream>>>(
        m2, gW2 + (size_t)t * HDIM * HDIM, gb2 + (size_t)t * HDIM, gbuf, NNODES);

    gru_step<8><<<(NNODES + 7) / 8, 384, 0, stream>>>(
        gbuf, hprev, Wx, Wh, bx, bh, hcur, NNODES);

    attn_update<<<NNODES, 128, 0, stream>>>(hcur, Waw, baw, out, sden, mxv);
  }

  attn_finalize<<<(NNODES * HDIM + 255) / 256, 256, 0, stream>>>(out, sden);
}